// Round 4
// baseline (40355.118 us; speedup 1.0000x reference)
//
#include <hip/hip_runtime.h>
#include <stdint.h>

#define T_LEN 8192
#define HID 512
#define NTAG 12
#define START_TAG 10
#define STOP_TAG 11
#define NEGV -10000.0f

// ws layout (bytes) — ~34 MB
#define HX_OFF    0u           // uint32 [2][T][512]: (tag<<16)|bf16(h)  = 33,554,432 B
#define FEATS_OFF 33554432u    // float [T][12]
#define CNT_OFF   33947648u    // int[64]: [32]=flagF32, [33]=flag64

__device__ __forceinline__ float blo(uint32_t u) {
    union { uint32_t i; float f; } x; x.i = u << 16; return x.f;
}
__device__ __forceinline__ float bhi(uint32_t u) {
    union { uint32_t i; float f; } x; x.i = u & 0xffff0000u; return x.f;
}
__device__ __forceinline__ float b2f(uint16_t u) {
    union { uint32_t i; float f; } x; x.i = ((uint32_t)u) << 16; return x.f;
}
__device__ __forceinline__ uint32_t rne16(float f) {   // f32 -> bf16 bits (RNE)
    union { float f; uint32_t i; } x; x.f = f;
    uint32_t u = x.i + 0x7FFFu + ((x.i >> 16) & 1u);
    return u >> 16;
}
__device__ __forceinline__ uint32_t pk(float f0, float f1) {
    return rne16(f0) | (rne16(f1) << 16);
}
__device__ __forceinline__ float fsig(float x) { return 1.0f / (1.0f + __expf(-x)); }
__device__ __forceinline__ float ftanh(float x) { return 1.0f - 2.0f / (1.0f + __expf(2.0f * x)); }

// -------- stage 0: dtype probe + flag/counter init
__global__ __launch_bounds__(256) void k_probe(
    const uint32_t* __restrict__ embw, const int* __restrict__ sent32, int* __restrict__ cnt)
{
    __shared__ int s_bf16, s_zero;
    const int tid = threadIdx.x;
    if (tid == 0) { s_bf16 = 0; s_zero = 0; }
    __syncthreads();
    uint32_t u = embw[tid * 97 + 5];
    float lo = b2f((uint16_t)(u & 0xFFFFu));
    float hi = b2f((uint16_t)(u >> 16));
    if (fabsf(lo) <= 8.0f && fabsf(hi) <= 8.0f) atomicAdd(&s_bf16, 1);
    if (sent32[2 * tid + 1] == 0) atomicAdd(&s_zero, 1);
    __syncthreads();
    if (tid == 0) {
        cnt[32] = (s_bf16 < 224) ? 1 : 0;   // 1 => floats are f32
        cnt[33] = (s_zero >= 250) ? 1 : 0;  // 1 => sent is int64
    }
    if (tid < 32) cnt[tid] = 0;
}

// -------- stage 1: fused BiLSTM scan, dataflow-sync via tagged h dwords.
// 32 WGs: dir=bid>>4, slice w=bid&15 owns h[w*32..w*32+32). Thread (rl,q):
// gate row grow = w*32+(rl&31)+512*(rl>>5), k-quarter q. W_hh (64 dwords) and
// W_ih (38 dwords) in VGPRs as packed bf16. Per step: poll own h-element dword
// (tag match => value valid, single round trip), 2 intra-WG barriers.
__global__ __launch_bounds__(512, 1) void k_scan(
    const int* __restrict__ sent, const void* __restrict__ emb,
    const void* __restrict__ wih_f, const void* __restrict__ whh_f,
    const void* __restrict__ b_f,
    const void* __restrict__ wih_b, const void* __restrict__ whh_b,
    const void* __restrict__ b_b,
    uint32_t* __restrict__ hx, int* __restrict__ cnt)
{
    __shared__ float  hbuf[512];
    __shared__ float4 partial[128];        // [row] = {q0,q1,q2,q3}
    __shared__ float  xbuf[2][304];        // [300..303] zero pad

    const int tid = threadIdx.x;
    const int dir = blockIdx.x >> 4;
    const int w   = blockIdx.x & 15;
    const int flagF32 = cnt[32];
    const int flag64  = cnt[33];
    const void* wih = dir ? wih_b : wih_f;
    const void* whh = dir ? whh_b : whh_f;
    const void* bb  = dir ? b_b  : b_f;
    uint32_t* hd = hx + (size_t)dir * T_LEN * HID;

    const int rl = tid & 127;
    const int q  = tid >> 7;
    const int grow = w * 32 + (rl & 31) + 512 * (rl >> 5);

    // W_hh slice -> VGPRs (packed bf16), k in [q*128, q*128+128)
    uint32_t wh[64];
    if (flagF32) {
        const float* src = (const float*)whh + (size_t)grow * HID + q * 128;
        #pragma unroll
        for (int kk = 0; kk < 64; ++kk) wh[kk] = pk(src[2 * kk], src[2 * kk + 1]);
    } else {
        const uint32_t* src = (const uint32_t*)((const uint16_t*)whh + (size_t)grow * HID + q * 128);
        #pragma unroll
        for (int kk = 0; kk < 64; ++kk) wh[kk] = src[kk];
    }
    // W_ih slice -> VGPRs: elements [q*76, q*76+76) of 300, tail zero
    uint32_t wi[38];
    if (flagF32) {
        const float* src = (const float*)wih + (size_t)grow * 300 + q * 76;
        #pragma unroll
        for (int kk = 0; kk < 38; ++kk) {
            int e = q * 76 + 2 * kk;
            float f0 = (e     < 300) ? src[2 * kk]     : 0.0f;
            float f1 = (e + 1 < 300) ? src[2 * kk + 1] : 0.0f;
            wi[kk] = pk(f0, f1);
        }
    } else {
        const uint32_t* src = (const uint32_t*)((const uint16_t*)wih + (size_t)grow * 300 + q * 76);
        #pragma unroll
        for (int kk = 0; kk < 38; ++kk)
            wi[kk] = (q * 76 + 2 * kk < 300) ? src[kk] : 0u;
    }
    const float bias = flagF32 ? ((const float*)bb)[grow] : b2f(((const uint16_t*)bb)[grow]);

    if (tid < 4) { xbuf[0][300 + tid] = 0.0f; xbuf[1][300 + tid] = 0.0f; }
    {   // x for step 0
        int idx0 = dir ? (T_LEN - 1) : 0;
        if (tid < 150) {
            int tok = flag64 ? sent[2 * idx0] : sent[idx0];
            if (flagF32) {
                float2 v = ((const float2*)((const float*)emb + (size_t)tok * 300))[tid];
                xbuf[0][2 * tid] = v.x; xbuf[0][2 * tid + 1] = v.y;
            } else {
                uint32_t v = ((const uint32_t*)((const uint16_t*)emb + (size_t)tok * 300))[tid];
                xbuf[0][2 * tid] = blo(v); xbuf[0][2 * tid + 1] = bhi(v);
            }
        }
    }
    __syncthreads();

    float c = 0.0f;

    for (int ts = 0; ts < T_LEN; ++ts) {
        const int idx  = dir ? (T_LEN - 1 - ts) : ts;
        const int slot = ts & 1;

        // (a) issue x prefetch for ts+1
        uint32_t nxtu = 0; float2 nxtf = make_float2(0.0f, 0.0f);
        if (tid < 150) {
            int ts2  = (ts + 1 < T_LEN) ? (ts + 1) : 0;
            int idx2 = dir ? (T_LEN - 1 - ts2) : ts2;
            int tok2 = flag64 ? sent[2 * idx2] : sent[idx2];
            if (flagF32)
                nxtf = ((const float2*)((const float*)emb + (size_t)tok2 * 300))[tid];
            else
                nxtu = ((const uint32_t*)((const uint16_t*)emb + (size_t)tok2 * 300))[tid];
        }

        // (b) x-dot: independent of h — fills the h store-visibility window
        float xdot = (q == 0) ? bias : 0.0f;
        {
            const float2* xs2 = (const float2*)(&xbuf[slot][q * 76]);
            #pragma unroll
            for (int kk = 0; kk < 38; ++kk) {
                float2 xv = xs2[kk];
                xdot += blo(wi[kk]) * xv.x + bhi(wi[kk]) * xv.y;
            }
        }

        // (c) poll own element of h_{ts-1}: tag and value in one dword
        if (ts > 0) {
            const int pidx = dir ? (T_LEN - ts) : (ts - 1);
            const uint32_t* src = hd + (size_t)pidx * HID + tid;
            const uint32_t expect = (uint32_t)ts << 16;
            uint32_t pv;
            do {
                pv = __hip_atomic_load(src, __ATOMIC_RELAXED, __HIP_MEMORY_SCOPE_AGENT);
            } while ((pv & 0xFFFF0000u) != expect);
            hbuf[tid] = blo(pv);
        } else {
            hbuf[tid] = 0.0f;
        }
        __syncthreads();                                   // B1

        {   // (d) hh matvec from LDS h (broadcast reads), weights in VGPRs
            const float4* hseg = (const float4*)(&hbuf[q * 128]);
            float acc = xdot;
            #pragma unroll
            for (int kk = 0; kk < 32; ++kk) {
                float4 h4 = hseg[kk];
                uint32_t a = wh[2 * kk], b = wh[2 * kk + 1];
                acc += blo(a) * h4.x + bhi(a) * h4.y;
                acc += blo(b) * h4.z + bhi(b) * h4.w;
            }
            ((float*)&partial[rl])[q] = acc;
        }
        if (tid < 150) {   // (e) commit x prefetch (ordered vs readers by B2/B1next)
            if (flagF32) {
                xbuf[slot ^ 1][2 * tid] = nxtf.x; xbuf[slot ^ 1][2 * tid + 1] = nxtf.y;
            } else {
                xbuf[slot ^ 1][2 * tid] = blo(nxtu); xbuf[slot ^ 1][2 * tid + 1] = bhi(nxtu);
            }
        }
        __syncthreads();                                   // B2

        if (tid < 32) {    // (f) gates + publish tagged h (earliest possible)
            float4 pi = partial[tid],      pf = partial[32 + tid];
            float4 pg = partial[64 + tid], po = partial[96 + tid];
            float gi = pi.x + pi.y + pi.z + pi.w;
            float gf = pf.x + pf.y + pf.z + pf.w;
            float gg = pg.x + pg.y + pg.z + pg.w;
            float go = po.x + po.y + po.z + po.w;
            c = fsig(gf) * c + fsig(gi) * ftanh(gg);
            float h = fsig(go) * ftanh(c);
            uint32_t pkd = ((uint32_t)(ts + 1) << 16) | rne16(h);
            __hip_atomic_store(&hd[(size_t)idx * HID + w * 32 + tid], pkd,
                               __ATOMIC_RELAXED, __HIP_MEMORY_SCOPE_AGENT);
        }
        // no trailing barrier: B1 of next iter orders hbuf/partial reuse
    }
}

// -------- stage 2: feats[t] = log_softmax(W_proj @ [hf;hb] + b_proj)
__global__ __launch_bounds__(256) void k_feats(
    const uint32_t* __restrict__ hx, const void* __restrict__ wproj,
    const void* __restrict__ bproj, const int* __restrict__ cnt,
    float* __restrict__ feats)
{
    const int flagF32 = cnt[32];
    const int lane = threadIdx.x & 63;
    const int t = blockIdx.x * 4 + (threadIdx.x >> 6);
    const uint32_t* hf = hx;
    const uint32_t* hb = hx + (size_t)T_LEN * HID;
    float z[NTAG];
    #pragma unroll
    for (int j = 0; j < NTAG; ++j) z[j] = 0.0f;
    if (flagF32) {
        const float* wp = (const float*)wproj;
        for (int kk = lane; kk < 2 * HID; kk += 64) {
            float hv = (kk < HID) ? blo(hf[(size_t)t * HID + kk])
                                  : blo(hb[(size_t)t * HID + kk - HID]);
            #pragma unroll
            for (int j = 0; j < NTAG; ++j) z[j] += wp[j * 2 * HID + kk] * hv;
        }
    } else {
        const uint16_t* wp = (const uint16_t*)wproj;
        for (int kk = lane; kk < 2 * HID; kk += 64) {
            float hv = (kk < HID) ? blo(hf[(size_t)t * HID + kk])
                                  : blo(hb[(size_t)t * HID + kk - HID]);
            #pragma unroll
            for (int j = 0; j < NTAG; ++j) z[j] += b2f(wp[j * 2 * HID + kk]) * hv;
        }
    }
    #pragma unroll
    for (int j = 0; j < NTAG; ++j) {
        #pragma unroll
        for (int s = 1; s < 64; s <<= 1) z[j] += __shfl_xor(z[j], s);
        z[j] += flagF32 ? ((const float*)bproj)[j] : b2f(((const uint16_t*)bproj)[j]);
    }
    float m = z[0];
    #pragma unroll
    for (int j = 1; j < NTAG; ++j) m = fmaxf(m, z[j]);
    float se = 0.0f;
    #pragma unroll
    for (int j = 0; j < NTAG; ++j) se += expf(z[j] - m);
    float lse = m + logf(se);
    if (lane == 0) {
        #pragma unroll
        for (int j = 0; j < NTAG; ++j)
            feats[(size_t)t * NTAG + j] = z[j] - lse;
    }
}

// -------- stage 3: Viterbi forward + backtrace, single wave
__global__ __launch_bounds__(64) void k_viterbi(
    const float* __restrict__ feats, const void* __restrict__ trans,
    const int* __restrict__ cnt, float* __restrict__ out)
{
    __shared__ unsigned long long prow[T_LEN];
    __shared__ float fbuf[448];
    const int flagF32 = cnt[32];
    const int l = threadIdx.x;
    const int jcol = (l < NTAG) ? l : 0;
    float trcol[NTAG], trstop[NTAG];
    if (flagF32) {
        const float* tr = (const float*)trans;
        #pragma unroll
        for (int i = 0; i < NTAG; ++i) { trcol[i] = tr[i * NTAG + jcol]; trstop[i] = tr[i * NTAG + STOP_TAG]; }
    } else {
        const uint16_t* tr = (const uint16_t*)trans;
        #pragma unroll
        for (int i = 0; i < NTAG; ++i) { trcol[i] = b2f(tr[i * NTAG + jcol]); trstop[i] = b2f(tr[i * NTAG + STOP_TAG]); }
    }
    float v[NTAG];
    #pragma unroll
    for (int i = 0; i < NTAG; ++i) v[i] = (i == START_TAG) ? 0.0f : NEGV;

    for (int t = 0; t < T_LEN; ++t) {
        if ((t & 31) == 0) {
            __syncthreads();
            #pragma unroll
            for (int r = 0; r < 6; ++r) {
                int g = l + r * 64;
                fbuf[g] = feats[t * NTAG + g];
            }
            __syncthreads();
        }
        float best = v[0] + trcol[0];
        int bi = 0;
        #pragma unroll
        for (int i = 1; i < NTAG; ++i) {
            float cand = v[i] + trcol[i];
            if (cand > best) { best = cand; bi = i; }   // strict >: first-index ties
        }
        float newv = best + fbuf[(t & 31) * NTAG + jcol];
        unsigned long long contrib = (l < NTAG) ? ((unsigned long long)bi << (4 * l)) : 0ull;
        #pragma unroll
        for (int s = 1; s < 16; s <<= 1) contrib |= __shfl_xor(contrib, s);
        if (l == 0) prow[t] = contrib;
        #pragma unroll
        for (int i = 0; i < NTAG; ++i) v[i] = __shfl(newv, i);
    }

    if (l == 0) {
        float best = v[0] + trstop[0];
        int bt = 0;
        #pragma unroll
        for (int i = 1; i < NTAG; ++i) {
            float cand = v[i] + trstop[i];
            if (cand > best) { best = cand; bt = i; }
        }
        out[0] = best;
        int tag = bt;
        out[T_LEN] = (float)tag;
        unsigned long long row = prow[T_LEN - 1];
        for (int t = T_LEN - 1; t >= 1; --t) {
            unsigned long long nxt = (t > 1) ? prow[t - 1] : 0ull;
            tag = (int)((row >> (4 * tag)) & 15ull);
            out[t] = (float)tag;
            row = nxt;
        }
    }
}

extern "C" void kernel_launch(void* const* d_in, const int* in_sizes, int n_in,
                              void* d_out, int out_size, void* d_ws, size_t ws_size,
                              hipStream_t stream)
{
    const int*  sent  = (const int*)d_in[0];
    const void* emb   = d_in[1];
    const void* wih_f = d_in[2];
    const void* whh_f = d_in[3];
    const void* b_f   = d_in[4];
    const void* wih_b = d_in[5];
    const void* whh_b = d_in[6];
    const void* b_b   = d_in[7];
    const void* wproj = d_in[8];
    const void* bproj = d_in[9];
    const void* trans = d_in[10];

    char* ws = (char*)d_ws;
    uint32_t* hx  = (uint32_t*)(ws + HX_OFF);
    float* feats  = (float*)(ws + FEATS_OFF);
    int*   cnt    = (int*)(ws + CNT_OFF);
    float* out    = (float*)d_out;

    k_probe<<<1, 256, 0, stream>>>((const uint32_t*)emb, sent, cnt);
    k_scan<<<32, 512, 0, stream>>>(sent, emb, wih_f, whh_f, b_f,
                                   wih_b, whh_b, b_b, hx, cnt);
    k_feats<<<T_LEN / 4, 256, 0, stream>>>(hx, wproj, bproj, cnt, feats);
    k_viterbi<<<1, 64, 0, stream>>>(feats, trans, cnt, out);
}